// Round 3
// baseline (1107.887 us; speedup 1.0000x reference)
//
#include <hip/hip_runtime.h>

// SoftDecisionTree: BATCH=1M, DIM=64, DEPTH=7 -> 127 nodes, 128 leaves.
// Round 3: logits via MFMA (f16 16x16x32). Block=256 threads (4 waves) owns 256
// rows, processed in 4 chunks of 64 rows:
//   stage:  x chunk -> LDS f16, XOR-swizzled rows (G4)
//   mfma :  wave w computes rows [16w,16w+16) x 128 node-cols; B-frags (weights,
//           f16, 64 VGPRs) hoisted once per block; sigmoid applied on C-frags;
//           p stored f16 in LDS [64 rows][stride 129] (walk reads 2-way = free)
//   walk :  wave w walks depth-2 subtree w for all 64 rows (lane = row);
//           33 p-reads/thread, 32 leaf probs buffered in 8 v4f regs, then
//           stored as one complete 128B line per lane (full-line writes).
// pred: per-wave partials reduced through LDS.

typedef float v4f __attribute__((ext_vector_type(4)));
typedef _Float16 h2 __attribute__((ext_vector_type(2)));
typedef _Float16 h8 __attribute__((ext_vector_type(8)));
typedef unsigned int u32;
typedef u32 u32x2 __attribute__((ext_vector_type(2)));
typedef u32 u32x4 __attribute__((ext_vector_type(4)));

constexpr int BATCH = 1 << 20;

// LDS layout (bytes)
constexpr int X_OFF = 0;                       // 64 rows x 128B (f16, swizzled)
constexpr int W_OFF = 8192;                    // 128 rows x 128B (f16, swizzled)
constexpr int P_OFF = 8192 + 16384;            // 64 rows x 129 halves (stride 258B)
constexpr int PRED_OFF = P_OFF + 64 * 129 * 2; // 4*64 floats
constexpr int SMEM_BYTES = PRED_OFF + 4 * 64 * 4;

__device__ __forceinline__ float fast_sigmoid(float z) {
    float e = __builtin_amdgcn_exp2f(z * -1.44269504088896340736f);
    return __builtin_amdgcn_rcpf(1.0f + e);
}

__device__ __forceinline__ u32 pk(float a, float b) {
    return __builtin_bit_cast(u32, __builtin_amdgcn_cvt_pkrtz(a, b));
}

// DFS over the depth-5 subtree rooted at compile-time NODE (level 2).
// Leaves: NODE in [127,254], LI = NODE-127; LOFF = first leaf of this subtree.
template <int NODE, int LOFF>
struct Sub {
    __device__ __forceinline__ static void run(float prob, const _Float16* __restrict__ prow,
                                               const float* __restrict__ leaf,
                                               v4f* __restrict__ lpb, float& pred) {
        if constexpr (NODE >= 127) {
            constexpr int RI = NODE - 127 - LOFF;  // 0..31
            lpb[RI >> 2][RI & 3] = prob;
            pred = fmaf(prob, leaf[NODE - 127], pred);  // uniform scalar load
        } else {
            float p = (float)prow[NODE];  // ds_read_u16, const offset
            Sub<2 * NODE + 1, LOFF>::run(prob * (1.0f - p), prow, leaf, lpb, pred);
            Sub<2 * NODE + 2, LOFF>::run(prob * p,          prow, leaf, lpb, pred);
        }
    }
};

__global__ __launch_bounds__(256, 3) void sdt_kernel(
    const float* __restrict__ x,
    const float* __restrict__ w,
    const float* __restrict__ bias,
    const float* __restrict__ leaf,
    float* __restrict__ pred_out,
    float* __restrict__ lp_out)
{
    __shared__ __align__(16) unsigned char smem[SMEM_BYTES];

    const int tid  = threadIdx.x;
    const int lane = tid & 63;
    const int wave = tid >> 6;
    const int lc   = lane & 15;          // MFMA col / row-within-tile selector
    const int lq   = lane >> 4;          // K-chunk selector (0..3)
    const int block_row0 = blockIdx.x * 256;

    // ---- one-time: stage weights -> LDS f16 (swizzled), node 127 zeroed ----
    for (int idx = tid; idx < 127 * 16; idx += 256) {
        int node = idx >> 4, c8 = idx & 15;
        const float* sp = w + node * 64 + c8 * 4;
        float a = sp[0], b = sp[1], c = sp[2], d = sp[3];
        int addr = node * 128 + ((c8 * 8) ^ ((node & 7) << 4));
        *(u32x2*)(smem + W_OFF + addr) = u32x2{pk(a, b), pk(c, d)};
    }
    if (tid < 16) {
        int addr = 127 * 128 + ((tid * 8) ^ (7 << 4));
        *(u32x2*)(smem + W_OFF + addr) = u32x2{0u, 0u};
    }

    // bias per col-tile (node 127 is padding -> clamp index)
    float bias_v[8];
#pragma unroll
    for (int ct = 0; ct < 8; ++ct) {
        int bi = ct * 16 + lc;
        bias_v[ct] = bias[bi > 126 ? 126 : bi];
    }

    __syncthreads();

    // ---- hoist B fragments (8 col-tiles x 2 K-halves) into VGPRs ----
    h8 bfrag[8][2];
#pragma unroll
    for (int ct = 0; ct < 8; ++ct) {
#pragma unroll
        for (int kh = 0; kh < 2; ++kh) {
            int node = ct * 16 + lc;
            int bc = kh * 64 + lq * 16;
            bfrag[ct][kh] = *(const h8*)(smem + W_OFF + node * 128 + (bc ^ ((node & 7) << 4)));
        }
    }

    _Float16* pbase = (_Float16*)(smem + P_OFF);
    float* predlds  = (float*)(smem + PRED_OFF);

    for (int ck = 0; ck < 4; ++ck) {
        const int chunk_row0 = block_row0 + ck * 64;

        // ---- stage x chunk -> LDS f16 (swizzled) ----
        {
            int row = tid >> 2;        // 0..63
            int c4  = tid & 3;         // 16-float segment
            const v4f* src = (const v4f*)(x + (size_t)(chunk_row0 + row) * 64 + c4 * 16);
            v4f f0 = src[0], f1 = src[1], f2 = src[2], f3 = src[3];
            int sw = (row & 7) << 4;
            int bc0 = c4 * 32;
            *(u32x4*)(smem + X_OFF + row * 128 + (bc0 ^ sw)) =
                u32x4{pk(f0.x, f0.y), pk(f0.z, f0.w), pk(f1.x, f1.y), pk(f1.z, f1.w)};
            *(u32x4*)(smem + X_OFF + row * 128 + ((bc0 + 16) ^ sw)) =
                u32x4{pk(f2.x, f2.y), pk(f2.z, f2.w), pk(f3.x, f3.y), pk(f3.z, f3.w)};
        }
        __syncthreads();

        // ---- MFMA: wave computes rows [16*wave, +16) x 128 cols ----
        {
            int row = wave * 16 + lc;
            int sw = (row & 7) << 4;
            int bc = lq * 16;
            h8 a0 = *(const h8*)(smem + X_OFF + row * 128 + (bc ^ sw));
            h8 a1 = *(const h8*)(smem + X_OFF + row * 128 + ((bc + 64) ^ sw));
            int rowb = wave * 16 + lq * 4;
#pragma unroll
            for (int ct = 0; ct < 8; ++ct) {
                v4f acc = {};
                acc = __builtin_amdgcn_mfma_f32_16x16x32_f16(a0, bfrag[ct][0], acc, 0, 0, 0);
                acc = __builtin_amdgcn_mfma_f32_16x16x32_f16(a1, bfrag[ct][1], acc, 0, 0, 0);
                int col = ct * 16 + lc;
#pragma unroll
                for (int i = 0; i < 4; ++i) {
                    float p = fast_sigmoid(acc[i] + bias_v[ct]);
                    pbase[(rowb + i) * 129 + col] = (_Float16)p;  // C layout: col=lane&15, row=(lane>>4)*4+i
                }
            }
        }
        __syncthreads();

        // ---- walk: wave `wave` handles depth-2 subtree `wave`, lane = row ----
        {
            const _Float16* prow = pbase + lane * 129;
            float p0  = (float)prow[0];
            float pl1 = (float)prow[1 + (wave >> 1)];
            float pre = (wave >= 2 ? p0 : 1.0f - p0) * ((wave & 1) ? pl1 : 1.0f - pl1);

            float pred_part = 0.0f;
            v4f lpb[8];
            switch (wave) {
                case 0: Sub<3, 0 >::run(pre, prow, leaf, lpb, pred_part); break;
                case 1: Sub<4, 32>::run(pre, prow, leaf, lpb, pred_part); break;
                case 2: Sub<5, 64>::run(pre, prow, leaf, lpb, pred_part); break;
                default: Sub<6, 96>::run(pre, prow, leaf, lpb, pred_part); break;
            }

            v4f* dst = (v4f*)(lp_out + (size_t)(chunk_row0 + lane) * 128 + wave * 32);
#pragma unroll
            for (int i = 0; i < 8; ++i)
                __builtin_nontemporal_store(lpb[i], dst + i);  // lane writes its full 128B line

            predlds[wave * 64 + lane] = pred_part;
        }
        __syncthreads();

        if (tid < 64) {
            float s = predlds[tid] + predlds[64 + tid] + predlds[128 + tid] + predlds[192 + tid];
            pred_out[chunk_row0 + tid] = s;
        }
        // next chunk's staging writes X region only; all reads of X/P finished
        // before the barrier above.
    }
}

extern "C" void kernel_launch(void* const* d_in, const int* in_sizes, int n_in,
                              void* d_out, int out_size, void* d_ws, size_t ws_size,
                              hipStream_t stream) {
    const float* x    = (const float*)d_in[0];
    const float* w    = (const float*)d_in[1];
    const float* bias = (const float*)d_in[2];
    const float* leaf = (const float*)d_in[3];

    float* pred = (float*)d_out;             // BATCH floats
    float* lp   = (float*)d_out + BATCH;     // BATCH x 128 floats

    sdt_kernel<<<BATCH / 256, 256, 0, stream>>>(x, w, bias, leaf, pred, lp);
}

// Round 4
// 183.407 us; speedup vs baseline: 6.0406x; 6.0406x over previous
//
#include <hip/hip_runtime.h>

// SoftDecisionTree: BATCH=1M, DIM=64, DEPTH=7 -> 127 nodes, 128 leaves.
// Round 4: MFMA logits + line-complete stores, zero barriers.
//   - Per block: 4 independent waves. Per chunk, wave w owns 16 rows.
//   - B-frags (weights f16) hoisted to VGPRs once; A-frags loaded from global.
//   - p = sigmoid(logits) stored f16 in per-wave LDS [node][row16] (stride 40B).
//   - Walk remapped: lane = (rsub=row-octet, j=leaf-quad). Each thread computes
//     4 leaves per (row,seg) pair from an 8-read root->leaf path product.
//     Store: one v4f per (row,seg); lanes j=0..7 tile a complete 128B line
//     => every store instruction writes 8 full lines (round-1/3 lesson).
//   - pred: 4 leaf-FMAs per pair, shfl_xor reduce over j, lane j==0 stores.
// No __syncthreads: each wave reads only the P region it wrote (same-wave DS
// ops are processed in order).

typedef float v4f __attribute__((ext_vector_type(4)));
typedef _Float16 h8 __attribute__((ext_vector_type(8)));
typedef unsigned int u32;
typedef u32 u32x2 __attribute__((ext_vector_type(2)));

constexpr int BATCH = 1 << 20;
constexpr int PSTRIDE = 40;           // bytes per node: 16 rows * 2B + 8 pad (b64-aligned)
constexpr int PWAVE = 128 * PSTRIDE;  // 5120 B per wave

__device__ __forceinline__ float fast_sigmoid(float z) {
    float e = __builtin_amdgcn_exp2f(z * -1.44269504088896340736f);
    return __builtin_amdgcn_rcpf(1.0f + e);
}

__global__ __launch_bounds__(256) void sdt_kernel(
    const float* __restrict__ x,
    const float* __restrict__ w,
    const float* __restrict__ bias,
    const float* __restrict__ leaf,
    float* __restrict__ pred_out,
    float* __restrict__ lp_out)
{
    __shared__ __align__(16) unsigned char smem[4 * PWAVE];

    const int tid  = threadIdx.x;
    const int lane = tid & 63;
    const int wave = tid >> 6;
    const int lc = lane & 15, lq = lane >> 4;   // MFMA fragment coords
    const int j = lane & 7,   rsub = lane >> 3; // walk coords

    unsigned char* Pw = smem + wave * PWAVE;

    // ---- one-time: hoist B fragments (weights, f16) into VGPRs ----
    h8 bfrag[8][2];
#pragma unroll
    for (int ct = 0; ct < 8; ++ct) {
        int node = ct * 16 + lc; if (node > 126) node = 126;  // col 127 = don't-care pad
#pragma unroll
        for (int kh = 0; kh < 2; ++kh) {
            const float* src = w + node * 64 + kh * 32 + lq * 8;
            v4f f0 = *(const v4f*)src;
            v4f f1 = *(const v4f*)(src + 4);
            h8 b;
#pragma unroll
            for (int t = 0; t < 4; ++t) { b[t] = (_Float16)f0[t]; b[4 + t] = (_Float16)f1[t]; }
            bfrag[ct][kh] = b;
        }
    }
    float bias_v[8];
#pragma unroll
    for (int ct = 0; ct < 8; ++ct) {
        int node = ct * 16 + lc; if (node > 126) node = 126;
        bias_v[ct] = bias[node];
    }
    v4f leafv[4];
#pragma unroll
    for (int s = 0; s < 4; ++s) leafv[s] = *(const v4f*)(leaf + 32 * s + 4 * j);

    const int b2 = (j >> 2) & 1, b3 = (j >> 1) & 1, b4 = j & 1;

    for (int ck = 0; ck < 4; ++ck) {
        const int row0 = blockIdx.x * 256 + ck * 64 + wave * 16;

        // ---- A fragments straight from global (f32 -> f16) ----
        const float* xr = x + (size_t)(row0 + lc) * 64 + lq * 8;
        v4f xa = *(const v4f*)xr,        xb = *(const v4f*)(xr + 4);
        v4f xc = *(const v4f*)(xr + 32), xd = *(const v4f*)(xr + 36);
        h8 a0, a1;
#pragma unroll
        for (int t = 0; t < 4; ++t) {
            a0[t] = (_Float16)xa[t]; a0[4 + t] = (_Float16)xb[t];
            a1[t] = (_Float16)xc[t]; a1[4 + t] = (_Float16)xd[t];
        }

        // ---- MFMA: 16 rows x 128 node-cols; sigmoid; p -> LDS f16 ----
#pragma unroll
        for (int ct = 0; ct < 8; ++ct) {
            v4f acc = {};
            acc = __builtin_amdgcn_mfma_f32_16x16x32_f16(a0, bfrag[ct][0], acc, 0, 0, 0);
            acc = __builtin_amdgcn_mfma_f32_16x16x32_f16(a1, bfrag[ct][1], acc, 0, 0, 0);
            union { _Float16 h[4]; u32x2 wrd; } u;
#pragma unroll
            for (int i = 0; i < 4; ++i)        // C layout: col=lane&15, row=(lane>>4)*4+i
                u.h[i] = (_Float16)fast_sigmoid(acc[i] + bias_v[ct]);
            *(u32x2*)(Pw + (ct * 16 + lc) * PSTRIDE + lq * 8) = u.wrd;  // ds_write_b64
        }

        asm volatile("s_waitcnt lgkmcnt(0)" ::: "memory");  // P visible (same-wave, belt+braces)

        // ---- walk: thread = (row octet rsub, leaf quad j) ----
        auto rd = [&](int node, int row) -> float {
            return (float)*(const _Float16*)(Pw + node * PSTRIDE + row * 2);
        };

        float pa = 0.f, pb = 0.f;
#pragma unroll
        for (int i1 = 0; i1 < 2; ++i1) {
            const int row = rsub + 8 * i1;
            float p0  = rd(0, row);
            float p1a = rd(1, row), p1b = rd(2, row);
            float f01_0 = (1.f - p0) * (1.f - p1a);
            float f01_1 = (1.f - p0) * p1a;
            float f01_2 = p0 * (1.f - p1b);
            float f01_3 = p0 * p1b;
            float acc = 0.f;
            v4f* dst = (v4f*)lp_out + (size_t)(row0 + row) * 32 + j;
#pragma unroll
            for (int seg = 0; seg < 4; ++seg) {
                float f01 = seg == 0 ? f01_0 : seg == 1 ? f01_1 : seg == 2 ? f01_2 : f01_3;
                float pd2 = rd(3 + seg, row);
                float P3 = f01 * (b2 ? pd2 : 1.f - pd2);
                float pd3 = rd(7 + 2 * seg + (j >> 2), row);
                float P4 = P3 * (b3 ? pd3 : 1.f - pd3);
                float pd4 = rd(15 + 4 * seg + (j >> 1), row);
                float P5 = P4 * (b4 ? pd4 : 1.f - pd4);
                const int q = 8 * seg + j;
                float pd5 = rd(31 + q, row);
                float A = P5 * (1.f - pd5), B = P5 * pd5;
                float pl = rd(63 + 2 * q, row), pr = rd(64 + 2 * q, row);
                v4f o = { A * (1.f - pl), A * pl, B * (1.f - pr), B * pr };
                __builtin_nontemporal_store(o, dst + seg * 8);  // lanes j=0..7 => 8 full 128B lines
                acc = fmaf(o.x, leafv[seg].x, acc);
                acc = fmaf(o.y, leafv[seg].y, acc);
                acc = fmaf(o.z, leafv[seg].z, acc);
                acc = fmaf(o.w, leafv[seg].w, acc);
            }
            if (i1 == 0) pa = acc; else pb = acc;
        }

        // pred: reduce over the 8 j-lanes of each row
#pragma unroll
        for (int s = 1; s <= 4; s <<= 1) {
            pa += __shfl_xor(pa, s, 64);
            pb += __shfl_xor(pb, s, 64);
        }
        if (j == 0) {
            pred_out[row0 + rsub]     = pa;
            pred_out[row0 + rsub + 8] = pb;
        }
    }
}

extern "C" void kernel_launch(void* const* d_in, const int* in_sizes, int n_in,
                              void* d_out, int out_size, void* d_ws, size_t ws_size,
                              hipStream_t stream) {
    const float* x    = (const float*)d_in[0];
    const float* w    = (const float*)d_in[1];
    const float* bias = (const float*)d_in[2];
    const float* leaf = (const float*)d_in[3];

    float* pred = (float*)d_out;             // BATCH floats
    float* lp   = (float*)d_out + BATCH;     // BATCH x 128 floats

    sdt_kernel<<<BATCH / 256, 256, 0, stream>>>(x, w, bias, leaf, pred, lp);
}

// Round 6
// 177.523 us; speedup vs baseline: 6.2408x; 1.0331x over previous
//
#include <hip/hip_runtime.h>

// SoftDecisionTree: BATCH=1M, DIM=64, DEPTH=7 -> 127 nodes, 128 leaves.
// Round 6 = round 5 with the cvt_pkrtz type fix (bit_cast through u32; the
// builtin returns __fp16x2, not _Float16x2).
//   - MFMA logits, line-complete NT stores, zero barriers (round 4 base).
//   - Software pipelining: x loads for chunk ck+1 issued right after chunk ck's
//     raw regs are consumed by cvt; MFMA+walk (~1000 cyc) hide HBM latency.
//   - Packed f32->f16 converts (v_cvt_pkrtz) everywhere.
//   - __launch_bounds__(256,3): cap VGPRs spill-free, 12 waves/CU.

typedef float v4f __attribute__((ext_vector_type(4)));
typedef _Float16 h8 __attribute__((ext_vector_type(8)));
typedef unsigned int u32;
typedef u32 u32x2 __attribute__((ext_vector_type(2)));

constexpr int BATCH = 1 << 20;
constexpr int PSTRIDE = 40;           // bytes per node: 16 rows * 2B + 8 pad
constexpr int PWAVE = 128 * PSTRIDE;  // 5120 B per wave

__device__ __forceinline__ float fast_sigmoid(float z) {
    float e = __builtin_amdgcn_exp2f(z * -1.44269504088896340736f);
    return __builtin_amdgcn_rcpf(1.0f + e);
}

__device__ __forceinline__ u32 pk2(float a, float b) {
    return __builtin_bit_cast(u32, __builtin_amdgcn_cvt_pkrtz(a, b));
}

__device__ __forceinline__ h8 cvt8(v4f lo, v4f hi) {
    union { u32 w[4]; h8 v; } u;
    u.w[0] = pk2(lo.x, lo.y);
    u.w[1] = pk2(lo.z, lo.w);
    u.w[2] = pk2(hi.x, hi.y);
    u.w[3] = pk2(hi.z, hi.w);
    return u.v;
}

__global__ __launch_bounds__(256, 3) void sdt_kernel(
    const float* __restrict__ x,
    const float* __restrict__ w,
    const float* __restrict__ bias,
    const float* __restrict__ leaf,
    float* __restrict__ pred_out,
    float* __restrict__ lp_out)
{
    __shared__ __align__(16) unsigned char smem[4 * PWAVE];

    const int tid  = threadIdx.x;
    const int lane = tid & 63;
    const int wave = tid >> 6;
    const int lc = lane & 15, lq = lane >> 4;   // MFMA fragment coords
    const int j = lane & 7,   rsub = lane >> 3; // walk coords

    unsigned char* Pw = smem + wave * PWAVE;

    // ---- one-time: hoist B fragments (weights, f16) into VGPRs ----
    h8 bfrag[8][2];
#pragma unroll
    for (int ct = 0; ct < 8; ++ct) {
        int node = ct * 16 + lc; if (node > 126) node = 126;  // col 127 = pad
#pragma unroll
        for (int kh = 0; kh < 2; ++kh) {
            const float* src = w + node * 64 + kh * 32 + lq * 8;
            bfrag[ct][kh] = cvt8(*(const v4f*)src, *(const v4f*)(src + 4));
        }
    }
    float bias_v[8];
#pragma unroll
    for (int ct = 0; ct < 8; ++ct) {
        int node = ct * 16 + lc; if (node > 126) node = 126;
        bias_v[ct] = bias[node];
    }
    v4f leafv[4];
#pragma unroll
    for (int s = 0; s < 4; ++s) leafv[s] = *(const v4f*)(leaf + 32 * s + 4 * j);

    const int b2 = (j >> 2) & 1, b3 = (j >> 1) & 1, b4 = j & 1;
    const int wave_row0 = blockIdx.x * 256 + wave * 16;   // chunk ck adds ck*64

    // ---- prologue: issue chunk-0 x loads ----
    const float* xr0 = x + (size_t)(wave_row0 + lc) * 64 + lq * 8;
    v4f xa = *(const v4f*)xr0,        xb = *(const v4f*)(xr0 + 4);
    v4f xc = *(const v4f*)(xr0 + 32), xd = *(const v4f*)(xr0 + 36);

#pragma unroll
    for (int ck = 0; ck < 4; ++ck) {
        const int row0 = wave_row0 + ck * 64;

        // consume raw regs (vmcnt wait lands here), then immediately re-issue
        // loads for chunk ck+1 -> MFMA+walk (~1000 cyc) hide their latency
        h8 a0 = cvt8(xa, xb);
        h8 a1 = cvt8(xc, xd);
        if (ck < 3) {
            const float* xr = xr0 + (ck + 1) * 64 * 64;
            xa = *(const v4f*)xr;        xb = *(const v4f*)(xr + 4);
            xc = *(const v4f*)(xr + 32); xd = *(const v4f*)(xr + 36);
        }

        // ---- MFMA: 16 rows x 128 node-cols; sigmoid; p -> LDS f16 ----
#pragma unroll
        for (int ct = 0; ct < 8; ++ct) {
            v4f acc = {};
            acc = __builtin_amdgcn_mfma_f32_16x16x32_f16(a0, bfrag[ct][0], acc, 0, 0, 0);
            acc = __builtin_amdgcn_mfma_f32_16x16x32_f16(a1, bfrag[ct][1], acc, 0, 0, 0);
            // C layout: col = lane&15, row = (lane>>4)*4 + i
            float s0 = fast_sigmoid(acc[0] + bias_v[ct]);
            float s1 = fast_sigmoid(acc[1] + bias_v[ct]);
            float s2 = fast_sigmoid(acc[2] + bias_v[ct]);
            float s3 = fast_sigmoid(acc[3] + bias_v[ct]);
            *(u32x2*)(Pw + (ct * 16 + lc) * PSTRIDE + lq * 8) =
                u32x2{pk2(s0, s1), pk2(s2, s3)};               // ds_write_b64
        }

        asm volatile("s_waitcnt lgkmcnt(0)" ::: "memory");  // P visible (same-wave)

        // ---- walk: thread = (row octet rsub, leaf quad j) ----
        auto rd = [&](int node, int row) -> float {
            return (float)*(const _Float16*)(Pw + node * PSTRIDE + row * 2);
        };

        float pa = 0.f, pb = 0.f;
#pragma unroll
        for (int i1 = 0; i1 < 2; ++i1) {
            const int row = rsub + 8 * i1;
            float p0  = rd(0, row);
            float p1a = rd(1, row), p1b = rd(2, row);
            float f01_0 = (1.f - p0) * (1.f - p1a);
            float f01_1 = (1.f - p0) * p1a;
            float f01_2 = p0 * (1.f - p1b);
            float f01_3 = p0 * p1b;
            float acc = 0.f;
            v4f* dst = (v4f*)lp_out + (size_t)(row0 + row) * 32 + j;
#pragma unroll
            for (int seg = 0; seg < 4; ++seg) {
                float f01 = seg == 0 ? f01_0 : seg == 1 ? f01_1 : seg == 2 ? f01_2 : f01_3;
                float pd2 = rd(3 + seg, row);
                float P3 = f01 * (b2 ? pd2 : 1.f - pd2);
                float pd3 = rd(7 + 2 * seg + (j >> 2), row);
                float P4 = P3 * (b3 ? pd3 : 1.f - pd3);
                float pd4 = rd(15 + 4 * seg + (j >> 1), row);
                float P5 = P4 * (b4 ? pd4 : 1.f - pd4);
                const int q = 8 * seg + j;
                float pd5 = rd(31 + q, row);
                float A = P5 * (1.f - pd5), B = P5 * pd5;
                float pl = rd(63 + 2 * q, row), pr = rd(64 + 2 * q, row);
                v4f o = { A * (1.f - pl), A * pl, B * (1.f - pr), B * pr };
                __builtin_nontemporal_store(o, dst + seg * 8);  // j=0..7 => 8 full 128B lines
                acc = fmaf(o.x, leafv[seg].x, acc);
                acc = fmaf(o.y, leafv[seg].y, acc);
                acc = fmaf(o.z, leafv[seg].z, acc);
                acc = fmaf(o.w, leafv[seg].w, acc);
            }
            if (i1 == 0) pa = acc; else pb = acc;
        }

        // pred: reduce over the 8 j-lanes of each row
#pragma unroll
        for (int s = 1; s <= 4; s <<= 1) {
            pa += __shfl_xor(pa, s, 64);
            pb += __shfl_xor(pb, s, 64);
        }
        if (j == 0) {
            pred_out[row0 + rsub]     = pa;
            pred_out[row0 + rsub + 8] = pb;
        }
    }
}

extern "C" void kernel_launch(void* const* d_in, const int* in_sizes, int n_in,
                              void* d_out, int out_size, void* d_ws, size_t ws_size,
                              hipStream_t stream) {
    const float* x    = (const float*)d_in[0];
    const float* w    = (const float*)d_in[1];
    const float* bias = (const float*)d_in[2];
    const float* leaf = (const float*)d_in[3];

    float* pred = (float*)d_out;             // BATCH floats
    float* lp   = (float*)d_out + BATCH;     // BATCH x 128 floats

    sdt_kernel<<<BATCH / 256, 256, 0, stream>>>(x, w, bias, leaf, pred, lp);
}